// Round 4
// baseline (942.106 us; speedup 1.0000x reference)
//
#include <hip/hip_runtime.h>
#include <math.h>

// MoE gate, round 4: single fused kernel, canonical-GEMM staging.
//   grid = 256 blocks (64 tokens each), block = 1024 thr = 16 waves.
//   wave = (expert-group eg in [0,4)) x (k-quarter q in [0,4)).
//   lane = token. acc[16] = 16 experts over a 512-wide k range.
//   Per chunk (KC=32 per quarter): stage x[4 quarters][64 tok][32 k] into
//   LDS with coalesced float4 loads + XOR-swizzled rows (conflict-free
//   ds_read_b128 on the compute side). w read as broadcast float4 from
//   global (uniform per wave -> 1 TA transaction, L1-resident).
//   Reduce k-quarters via LDS atomicAdd into logits[64][64]; wave 0 does
//   top-8 (strict >, lax.top_k tie rule) + softmax-over-top8 + store.
// Round-3 lesson: per-lane-row x global loads are 64-line divergent and
// re-reads across blocks miss L3 (900 MB fetch). x must be staged once,
// coalesced.

#define H_DIM 2048
#define N_EXP 64
#define TOPK 8
#define TOK_TILE 64
#define NQ 4                    // k quarters
#define KQ (H_DIM / NQ)         // 512
#define KC 32                   // k per quarter per chunk
#define NC (KQ / KC)            // 16 chunks
#define EPG 16                  // experts per wave

__global__ __launch_bounds__(1024, 4) void moe_gate_kernel(
    const float* __restrict__ x, const float* __restrict__ w,
    float* __restrict__ out, int n_tokens) {
  __shared__ float xs[NQ][TOK_TILE][KC];   // 32 KB, XOR-swizzled rows
  __shared__ float logits[N_EXP * TOK_TILE];  // 16 KB

  const int lane = threadIdx.x & 63;
  const int wave = threadIdx.x >> 6;
  const int eg = wave & 3;      // expert group
  const int q = wave >> 2;      // k quarter
  const int t0 = blockIdx.x * TOK_TILE;

  for (int i = threadIdx.x; i < N_EXP * TOK_TILE; i += 1024) logits[i] = 0.f;

  float acc[EPG];
#pragma unroll
  for (int e = 0; e < EPG; ++e) acc[e] = 0.f;

  // w base for this wave's 16 experts x k-quarter (uniform per wave; compiler
  // can't prove it, so these stay vector broadcast loads - 1 transaction).
  const float* wbase = w + (size_t)(eg * EPG) * H_DIM + q * KQ;

#pragma unroll 1
  for (int c = 0; c < NC; ++c) {
    // ---- stage: 2048 float4s = 1024 thr x 2; lanes consecutive in k ----
    float4 v0, v1;
    int k4a, toka, qqa, k4b, tokb, qqb;
    {
      int f = threadIdx.x;
      k4a = f & 7; toka = (f >> 3) & 63; qqa = f >> 9;
      v0 = *(const float4*)(x + (size_t)(t0 + toka) * H_DIM + qqa * KQ +
                            c * KC + k4a * 4);
      f = threadIdx.x + 1024;
      k4b = f & 7; tokb = (f >> 3) & 63; qqb = f >> 9;
      v1 = *(const float4*)(x + (size_t)(t0 + tokb) * H_DIM + qqb * KQ +
                            c * KC + k4b * 4);
    }
    __syncthreads();  // previous chunk's readers done
    *(float4*)&xs[qqa][toka][(k4a ^ (toka & 7)) * 4] = v0;
    *(float4*)&xs[qqb][tokb][(k4b ^ (tokb & 7)) * 4] = v1;
    __syncthreads();  // staging visible

    // ---- compute: 16 experts x 32 k ----
#pragma unroll
    for (int k8 = 0; k8 < 4; ++k8) {
      const float4 xa =
          *(const float4*)&xs[q][lane][((2 * k8 + 0) ^ (lane & 7)) * 4];
      const float4 xb =
          *(const float4*)&xs[q][lane][((2 * k8 + 1) ^ (lane & 7)) * 4];
#pragma unroll
      for (int e = 0; e < EPG; ++e) {
        const float* wp = wbase + (size_t)e * H_DIM + c * KC + k8 * 8;
        const float4 wa = ((const float4*)wp)[0];
        const float4 wb = ((const float4*)wp)[1];
        float a = acc[e];
        a = fmaf(xa.x, wa.x, a);
        a = fmaf(xa.y, wa.y, a);
        a = fmaf(xa.z, wa.z, a);
        a = fmaf(xa.w, wa.w, a);
        a = fmaf(xb.x, wb.x, a);
        a = fmaf(xb.y, wb.y, a);
        a = fmaf(xb.z, wb.z, a);
        a = fmaf(xb.w, wb.w, a);
        acc[e] = a;
      }
    }
  }

  // ---- reduce 4 k-quarters per (expert, token) ----
#pragma unroll
  for (int e = 0; e < EPG; ++e)
    atomicAdd(&logits[(eg * EPG + e) * TOK_TILE + lane], acc[e]);
  __syncthreads();

  if (wave != 0) return;

  // ---- wave 0: per-lane top-8 + softmax-over-top8 (lane = token) ----
  float lg[N_EXP];
#pragma unroll
  for (int e = 0; e < N_EXP; ++e) lg[e] = logits[e * TOK_TILE + lane];

  float bw[TOPK];
  int bi[TOPK];
#pragma unroll
  for (int k = 0; k < TOPK; ++k) {
    float m = lg[0];
    int mi = 0;
#pragma unroll
    for (int e = 1; e < N_EXP; ++e) {
      if (lg[e] > m) {  // strict > keeps lowest index on tie (lax.top_k)
        m = lg[e];
        mi = e;
      }
    }
    bw[k] = m;
    bi[k] = mi;
#pragma unroll
    for (int e = 0; e < N_EXP; ++e)
      if (e == mi) lg[e] = -INFINITY;
  }

  const float mx = bw[0];
  float ew[TOPK];
  float s = 0.f;
#pragma unroll
  for (int k = 0; k < TOPK; ++k) {
    ew[k] = expf(bw[k] - mx);
    s += ew[k];
  }
  const float inv = 1.f / s;

  const int t = t0 + lane;
  float4 w0, w1, i0, i1;
  w0.x = ew[0] * inv; w0.y = ew[1] * inv; w0.z = ew[2] * inv; w0.w = ew[3] * inv;
  w1.x = ew[4] * inv; w1.y = ew[5] * inv; w1.z = ew[6] * inv; w1.w = ew[7] * inv;
  i0.x = (float)bi[0]; i0.y = (float)bi[1]; i0.z = (float)bi[2]; i0.w = (float)bi[3];
  i1.x = (float)bi[4]; i1.y = (float)bi[5]; i1.z = (float)bi[6]; i1.w = (float)bi[7];

  float4* ow = reinterpret_cast<float4*>(out + (size_t)t * TOPK);
  ow[0] = w0;
  ow[1] = w1;
  float4* oi =
      reinterpret_cast<float4*>(out + (size_t)n_tokens * TOPK + (size_t)t * TOPK);
  oi[0] = i0;
  oi[1] = i1;
}

extern "C" void kernel_launch(void* const* d_in, const int* in_sizes, int n_in,
                              void* d_out, int out_size, void* d_ws,
                              size_t ws_size, hipStream_t stream) {
  const float* x = (const float*)d_in[0];
  const float* w = (const float*)d_in[1];
  float* out = (float*)d_out;
  const int n_tokens = in_sizes[0] / H_DIM;     // 16384
  const int n_blocks = n_tokens / TOK_TILE;     // 256
  moe_gate_kernel<<<n_blocks, 1024, 0, stream>>>(x, w, out, n_tokens);
}

// Round 6
// 888.867 us; speedup vs baseline: 1.0599x; 1.0599x over previous
//
#include <hip/hip_runtime.h>
#include <math.h>

// MoE gate, round 5 (resubmit — round 5 bench was a broker timeout, no data):
// lane = EXPERT (E=64 = wave width).
//   grid = 256 blocks (64-token tile each), block = 1024 thr = 16 waves.
//   wave ws owns k-slice [ws*128, ws*128+128); acc[64] = one partial logit
//   per token, expert = lane.
//   w:  per-lane row (w[lane][k]) -> 2 divergent dwordx4 per 512 FMAs
//       (128 cache lines / 1024 VALU cyc = ~12% of the TA path).
//   x:  wave-uniform addresses (readfirstlane k-base + literal t offsets)
//       -> scalar s_load into SGPRs; v_fmac_f32 v,s,v takes SGPR src free.
//       Zero TA traffic, zero VGPR cost. (Rounds 2-4 lesson: per-lane
//       divergent dwordx4 = 64 lines/instr saturates TA at ~1 line/cyc/CU.)
//   Reduce 16 k-slices via LDS atomicAdd into logits[64][68] (pad 68: write
//   lane-consecutive = conflict-free, 272 B rows stay 16 B aligned).
//   Wave 0: per-lane (lane = token) top-8, strict > (lax.top_k tie rule),
//   softmax over top-8 == full softmax renormalized (exact).

#define H_DIM 2048
#define N_EXP 64
#define TOPK 8
#define TT 64                 // tokens per block
#define NW 16                 // waves per block
#define KS (H_DIM / NW)       // 128 k per wave
#define KC 8                  // k per chunk
#define NCH (KS / KC)         // 16 chunks
#define LPAD (N_EXP + 4)      // 68

__global__ __launch_bounds__(1024, 4) void moe_gate_kernel(
    const float* __restrict__ x, const float* __restrict__ w,
    float* __restrict__ out, int n_tokens) {
  __shared__ float logits[TT][LPAD];  // 17.4 KB

  const int lane = threadIdx.x & 63;
  const int wave = threadIdx.x >> 6;
  const int t0 = blockIdx.x * TT;

  for (int i = threadIdx.x; i < TT * LPAD; i += 1024)
    (&logits[0][0])[i] = 0.f;
  __syncthreads();

  const int kbase = __builtin_amdgcn_readfirstlane(wave * KS);

  float acc[TT];
#pragma unroll
  for (int t = 0; t < TT; ++t) acc[t] = 0.f;

  const float* wrow = w + (size_t)lane * H_DIM + kbase;  // per-lane expert row
  const float* xbase = x + (size_t)t0 * H_DIM + kbase;   // wave-uniform

#pragma unroll 1
  for (int c = 0; c < NCH; ++c) {
    const float4 wa = *(const float4*)(wrow + c * KC);
    const float4 wb = *(const float4*)(wrow + c * KC + 4);
    const float* xc = xbase + c * KC;
#pragma unroll 8
    for (int t = 0; t < TT; ++t) {
      const float4 xa = *(const float4*)(xc + (size_t)t * H_DIM);      // s_load
      const float4 xb = *(const float4*)(xc + (size_t)t * H_DIM + 4);  // s_load
      float a = acc[t];
      a = fmaf(xa.x, wa.x, a);
      a = fmaf(xa.y, wa.y, a);
      a = fmaf(xa.z, wa.z, a);
      a = fmaf(xa.w, wa.w, a);
      a = fmaf(xb.x, wb.x, a);
      a = fmaf(xb.y, wb.y, a);
      a = fmaf(xb.z, wb.z, a);
      a = fmaf(xb.w, wb.w, a);
      acc[t] = a;
    }
  }

  // reduce the 16 k-slice partials: lane-consecutive addrs, conflict-free
#pragma unroll
  for (int t = 0; t < TT; ++t)
    atomicAdd(&logits[t][lane], acc[t]);
  __syncthreads();

  if (wave != 0) return;

  // ---- wave 0: per-lane top-8 + softmax-over-top8 (lane = token) ----
  float lg[N_EXP];
  const float4* lq = reinterpret_cast<const float4*>(&logits[lane][0]);
#pragma unroll
  for (int q = 0; q < N_EXP / 4; ++q) {
    float4 v = lq[q];
    lg[q * 4 + 0] = v.x;
    lg[q * 4 + 1] = v.y;
    lg[q * 4 + 2] = v.z;
    lg[q * 4 + 3] = v.w;
  }

  float bw[TOPK];
  int bi[TOPK];
#pragma unroll
  for (int k = 0; k < TOPK; ++k) {
    float m = lg[0];
    int mi = 0;
#pragma unroll
    for (int e = 1; e < N_EXP; ++e) {
      if (lg[e] > m) {  // strict > keeps lowest index on tie (lax.top_k)
        m = lg[e];
        mi = e;
      }
    }
    bw[k] = m;
    bi[k] = mi;
#pragma unroll
    for (int e = 0; e < N_EXP; ++e)
      if (e == mi) lg[e] = -INFINITY;
  }

  const float mx = bw[0];
  float ew[TOPK];
  float s = 0.f;
#pragma unroll
  for (int k = 0; k < TOPK; ++k) {
    ew[k] = expf(bw[k] - mx);
    s += ew[k];
  }
  const float inv = 1.f / s;

  const int t = t0 + lane;
  float4 w0, w1, i0, i1;
  w0.x = ew[0] * inv; w0.y = ew[1] * inv; w0.z = ew[2] * inv; w0.w = ew[3] * inv;
  w1.x = ew[4] * inv; w1.y = ew[5] * inv; w1.z = ew[6] * inv; w1.w = ew[7] * inv;
  i0.x = (float)bi[0]; i0.y = (float)bi[1]; i0.z = (float)bi[2]; i0.w = (float)bi[3];
  i1.x = (float)bi[4]; i1.y = (float)bi[5]; i1.z = (float)bi[6]; i1.w = (float)bi[7];

  float4* ow = reinterpret_cast<float4*>(out + (size_t)t * TOPK);
  ow[0] = w0;
  ow[1] = w1;
  float4* oi =
      reinterpret_cast<float4*>(out + (size_t)n_tokens * TOPK + (size_t)t * TOPK);
  oi[0] = i0;
  oi[1] = i1;
}

extern "C" void kernel_launch(void* const* d_in, const int* in_sizes, int n_in,
                              void* d_out, int out_size, void* d_ws,
                              size_t ws_size, hipStream_t stream) {
  const float* x = (const float*)d_in[0];
  const float* w = (const float*)d_in[1];
  float* out = (float*)d_out;
  const int n_tokens = in_sizes[0] / H_DIM;  // 16384
  const int n_blocks = n_tokens / TT;        // 256
  moe_gate_kernel<<<n_blocks, 1024, 0, stream>>>(x, w, out, n_tokens);
}

// Round 7
// 633.727 us; speedup vs baseline: 1.4866x; 1.4026x over previous
//
#include <hip/hip_runtime.h>
#include <math.h>

// MoE gate, round 7: round-5 structure with the token loop FULLY unrolled.
// Round-6 post-mortem: "#pragma unroll 8" left acc[] dynamically indexed ->
// LLVM demoted it to scratch (VGPR=56, WRITE_SIZE=1.1GB of spill traffic,
// VALUBusy 8.7%). Full unroll makes every acc index constant -> SROA keeps
// the 64 accumulators in VGPRs.
//
// Structure: lane = EXPERT (E=64 = wave width).
//   grid = 256 blocks (64-token tile), block = 1024 thr = 16 waves.
//   wave ws owns k-slice [ws*128, ws*128+128); acc[64] = partial logit per
//   token (expert = lane).
//   w: per-lane row -> 2 divergent dwordx4 per 512 FMAs (~12% of TA path).
//   x: wave-uniform addresses (readfirstlane k-base + literal t offsets) ->
//      scalar s_load (mergeable to s_load_dwordx8); v_fmac v,s,v takes the
//      SGPR operand for free. Zero TA traffic for x.
//   Reduce 16 k-slices via LDS atomicAdd into logits[64][68]; wave 0 does
//   top-8 (strict >, lax.top_k tie rule) + softmax over top-8 + store.

#define H_DIM 2048
#define N_EXP 64
#define TOPK 8
#define TT 64                 // tokens per block
#define NW 16                 // waves per block
#define KS (H_DIM / NW)       // 128 k per wave
#define KC 8                  // k per chunk
#define NCH (KS / KC)         // 16 chunks
#define LPAD (N_EXP + 4)      // 68

__global__ __launch_bounds__(1024, 4) void moe_gate_kernel(
    const float* __restrict__ x, const float* __restrict__ w,
    float* __restrict__ out, int n_tokens) {
  __shared__ float logits[TT][LPAD];  // 17.4 KB

  const int lane = threadIdx.x & 63;
  const int wave = threadIdx.x >> 6;
  const int t0 = blockIdx.x * TT;

  for (int i = threadIdx.x; i < TT * LPAD; i += 1024)
    (&logits[0][0])[i] = 0.f;
  __syncthreads();

  const int kbase = __builtin_amdgcn_readfirstlane(wave * KS);

  float acc[TT];
#pragma unroll
  for (int t = 0; t < TT; ++t) acc[t] = 0.f;

  const float* wrow = w + (size_t)lane * H_DIM + kbase;  // per-lane expert row
  const float* xbase = x + (size_t)t0 * H_DIM + kbase;   // wave-uniform

#pragma unroll 1
  for (int c = 0; c < NCH; ++c) {
    const float4 wa = *(const float4*)(wrow + c * KC);
    const float4 wb = *(const float4*)(wrow + c * KC + 4);
    const float* xc = xbase + c * KC;
#pragma unroll  // FULL unroll: constant trip count 64 -> static acc indices
    for (int t = 0; t < TT; ++t) {
      const float4 xa = *(const float4*)(xc + (size_t)t * H_DIM);      // s_load
      const float4 xb = *(const float4*)(xc + (size_t)t * H_DIM + 4);  // s_load
      float a = acc[t];
      a = fmaf(xa.x, wa.x, a);
      a = fmaf(xa.y, wa.y, a);
      a = fmaf(xa.z, wa.z, a);
      a = fmaf(xa.w, wa.w, a);
      a = fmaf(xb.x, wb.x, a);
      a = fmaf(xb.y, wb.y, a);
      a = fmaf(xb.z, wb.z, a);
      a = fmaf(xb.w, wb.w, a);
      acc[t] = a;
    }
  }

  // reduce the 16 k-slice partials: lane-consecutive addrs, conflict-free
#pragma unroll
  for (int t = 0; t < TT; ++t)
    atomicAdd(&logits[t][lane], acc[t]);
  __syncthreads();

  if (wave != 0) return;

  // ---- wave 0: per-lane top-8 + softmax-over-top8 (lane = token) ----
  float lg[N_EXP];
  const float4* lq = reinterpret_cast<const float4*>(&logits[lane][0]);
#pragma unroll
  for (int q = 0; q < N_EXP / 4; ++q) {
    float4 v = lq[q];
    lg[q * 4 + 0] = v.x;
    lg[q * 4 + 1] = v.y;
    lg[q * 4 + 2] = v.z;
    lg[q * 4 + 3] = v.w;
  }

  float bw[TOPK];
  int bi[TOPK];
#pragma unroll
  for (int k = 0; k < TOPK; ++k) {
    float m = lg[0];
    int mi = 0;
#pragma unroll
    for (int e = 1; e < N_EXP; ++e) {
      if (lg[e] > m) {  // strict > keeps lowest index on tie (lax.top_k)
        m = lg[e];
        mi = e;
      }
    }
    bw[k] = m;
    bi[k] = mi;
#pragma unroll
    for (int e = 0; e < N_EXP; ++e)
      if (e == mi) lg[e] = -INFINITY;
  }

  const float mx = bw[0];
  float ew[TOPK];
  float s = 0.f;
#pragma unroll
  for (int k = 0; k < TOPK; ++k) {
    ew[k] = expf(bw[k] - mx);
    s += ew[k];
  }
  const float inv = 1.f / s;

  const int t = t0 + lane;
  float4 w0, w1, i0, i1;
  w0.x = ew[0] * inv; w0.y = ew[1] * inv; w0.z = ew[2] * inv; w0.w = ew[3] * inv;
  w1.x = ew[4] * inv; w1.y = ew[5] * inv; w1.z = ew[6] * inv; w1.w = ew[7] * inv;
  i0.x = (float)bi[0]; i0.y = (float)bi[1]; i0.z = (float)bi[2]; i0.w = (float)bi[3];
  i1.x = (float)bi[4]; i1.y = (float)bi[5]; i1.z = (float)bi[6]; i1.w = (float)bi[7];

  float4* ow = reinterpret_cast<float4*>(out + (size_t)t * TOPK);
  ow[0] = w0;
  ow[1] = w1;
  float4* oi =
      reinterpret_cast<float4*>(out + (size_t)n_tokens * TOPK + (size_t)t * TOPK);
  oi[0] = i0;
  oi[1] = i1;
}

extern "C" void kernel_launch(void* const* d_in, const int* in_sizes, int n_in,
                              void* d_out, int out_size, void* d_ws,
                              size_t ws_size, hipStream_t stream) {
  const float* x = (const float*)d_in[0];
  const float* w = (const float*)d_in[1];
  float* out = (float*)d_out;
  const int n_tokens = in_sizes[0] / H_DIM;  // 16384
  const int n_blocks = n_tokens / TT;        // 256
  moe_gate_kernel<<<n_blocks, 1024, 0, stream>>>(x, w, out, n_tokens);
}

// Round 8
// 576.736 us; speedup vs baseline: 1.6335x; 1.0988x over previous
//
#include <hip/hip_runtime.h>
#include <math.h>

// MoE gate, round 8: R7 structure (lane = EXPERT, x wave-uniform) but x goes
// through VECTOR broadcast loads, not SMEM.
// R7 post-mortem: compiler scalarized x to s_load; SMEM is out-of-order so
// every batch needs s_waitcnt lgkmcnt(0) -> ~3000 stall cyc per 1024 FMA cyc,
// VALUBusy 24%, dur 500us. VMEM is in-order (vmcnt) and pipelines across the
// unrolled token loop. vzero asm poisons the base address so divergence
// analysis can't scalarize (R3-proven); all 64 lanes load the SAME address ->
// TA coalesces to 1 line-request per instr (no R3-style divergence blowup).
//
//   grid = 256 blocks (64-token tile), block = 512 thr = 8 waves.
//   wave ws owns k-slice [ws*256, ws*256+256); acc[64] = partial logit per
//   token (expert = lane). w: per-lane row, 2 divergent dwordx4 / 512 FMAs.
//   Reduce 8 k-slices via LDS atomicAdd into logits[64][68]; wave 0 does
//   top-8 (strict >, lax.top_k tie rule) + softmax over top-8 + store.
// __launch_bounds__(512,2): VGPR cap 256 (acc 64 + ~80 in-flight loads,
// anti-spill margin after R4/R6); 1 block/CU on all 256 CUs.

#define H_DIM 2048
#define N_EXP 64
#define TOPK 8
#define TT 64                 // tokens per block
#define NW 8                  // waves per block
#define KS (H_DIM / NW)       // 256 k per wave
#define KC 8                  // k per chunk
#define NCH (KS / KC)         // 32 chunks
#define LPAD (N_EXP + 4)      // 68

__global__ __launch_bounds__(512, 2) void moe_gate_kernel(
    const float* __restrict__ x, const float* __restrict__ w,
    float* __restrict__ out, int n_tokens) {
  __shared__ float logits[TT][LPAD];  // 17.4 KB

  const int lane = threadIdx.x & 63;
  const int wave = threadIdx.x >> 6;
  const int t0 = blockIdx.x * TT;

  for (int i = threadIdx.x; i < TT * LPAD; i += 512)
    (&logits[0][0])[i] = 0.f;
  __syncthreads();

  const int kbase = wave * KS;

  // Lane-opaque zero: forces x addresses to VGPRs -> vector broadcast loads
  // (64 identical lane addrs = 1 TA request), defeating SMEM scalarization.
  int vzero;
  asm("v_mov_b32 %0, 0" : "=v"(vzero));

  float acc[TT];
#pragma unroll
  for (int t = 0; t < TT; ++t) acc[t] = 0.f;

  const float* wrow = w + (size_t)lane * H_DIM + kbase;  // per-lane expert row
  const float* xbase = x + (size_t)t0 * H_DIM + kbase + vzero;  // VGPR-opaque

#pragma unroll 1
  for (int c = 0; c < NCH; ++c) {
    const float4 wa = *(const float4*)(wrow + c * KC);
    const float4 wb = *(const float4*)(wrow + c * KC + 4);
    const float* xc = xbase + c * KC;
#pragma unroll  // FULL unroll: constant acc indices (R6 lesson: partial
                // unroll -> dynamic index -> scratch demotion)
    for (int t = 0; t < TT; ++t) {
      const float4 xa = *(const float4*)(xc + (size_t)t * H_DIM);
      const float4 xb = *(const float4*)(xc + (size_t)t * H_DIM + 4);
      float a = acc[t];
      a = fmaf(xa.x, wa.x, a);
      a = fmaf(xa.y, wa.y, a);
      a = fmaf(xa.z, wa.z, a);
      a = fmaf(xa.w, wa.w, a);
      a = fmaf(xb.x, wb.x, a);
      a = fmaf(xb.y, wb.y, a);
      a = fmaf(xb.z, wb.z, a);
      a = fmaf(xb.w, wb.w, a);
      acc[t] = a;
    }
  }

  // reduce the 8 k-slice partials: lane-consecutive addrs, conflict-free
#pragma unroll
  for (int t = 0; t < TT; ++t)
    atomicAdd(&logits[t][lane], acc[t]);
  __syncthreads();

  if (wave != 0) return;

  // ---- wave 0: per-lane top-8 + softmax-over-top8 (lane = token) ----
  float lg[N_EXP];
  const float4* lq = reinterpret_cast<const float4*>(&logits[lane][0]);
#pragma unroll
  for (int q = 0; q < N_EXP / 4; ++q) {
    float4 v = lq[q];
    lg[q * 4 + 0] = v.x;
    lg[q * 4 + 1] = v.y;
    lg[q * 4 + 2] = v.z;
    lg[q * 4 + 3] = v.w;
  }

  float bw[TOPK];
  int bi[TOPK];
#pragma unroll
  for (int k = 0; k < TOPK; ++k) {
    float m = lg[0];
    int mi = 0;
#pragma unroll
    for (int e = 1; e < N_EXP; ++e) {
      if (lg[e] > m) {  // strict > keeps lowest index on tie (lax.top_k)
        m = lg[e];
        mi = e;
      }
    }
    bw[k] = m;
    bi[k] = mi;
#pragma unroll
    for (int e = 0; e < N_EXP; ++e)
      if (e == mi) lg[e] = -INFINITY;
  }

  const float mx = bw[0];
  float ew[TOPK];
  float s = 0.f;
#pragma unroll
  for (int k = 0; k < TOPK; ++k) {
    ew[k] = expf(bw[k] - mx);
    s += ew[k];
  }
  const float inv = 1.f / s;

  const int t = t0 + lane;
  float4 w0, w1, i0, i1;
  w0.x = ew[0] * inv; w0.y = ew[1] * inv; w0.z = ew[2] * inv; w0.w = ew[3] * inv;
  w1.x = ew[4] * inv; w1.y = ew[5] * inv; w1.z = ew[6] * inv; w1.w = ew[7] * inv;
  i0.x = (float)bi[0]; i0.y = (float)bi[1]; i0.z = (float)bi[2]; i0.w = (float)bi[3];
  i1.x = (float)bi[4]; i1.y = (float)bi[5]; i1.z = (float)bi[6]; i1.w = (float)bi[7];

  float4* ow = reinterpret_cast<float4*>(out + (size_t)t * TOPK);
  ow[0] = w0;
  ow[1] = w1;
  float4* oi =
      reinterpret_cast<float4*>(out + (size_t)n_tokens * TOPK + (size_t)t * TOPK);
  oi[0] = i0;
  oi[1] = i1;
}

extern "C" void kernel_launch(void* const* d_in, const int* in_sizes, int n_in,
                              void* d_out, int out_size, void* d_ws,
                              size_t ws_size, hipStream_t stream) {
  const float* x = (const float*)d_in[0];
  const float* w = (const float*)d_in[1];
  float* out = (float*)d_out;
  const int n_tokens = in_sizes[0] / H_DIM;  // 16384
  const int n_blocks = n_tokens / TT;        // 256
  moe_gate_kernel<<<n_blocks, 512, 0, stream>>>(x, w, out, n_tokens);
}